// Round 3
// baseline (595.928 us; speedup 1.0000x reference)
//
#include <hip/hip_runtime.h>
#include <cstdint>

#define Tt 1024
#define Hh 15
#define Ii 10
#define Oo 128
#define Bb 512

typedef float v2f __attribute__((ext_vector_type(2)));

__device__ __forceinline__ float sigmoidf_(float x) {
    return 1.0f / (1.0f + __expf(-x));
}
__device__ __forceinline__ float tanhf_(float x) {
    return 1.0f - 2.0f / (__expf(2.0f * x) + 1.0f);
}

// DPP row-rotate of a float within the 16-lane row. j must be a literal.
#define ROT(x, j) __int_as_float(__builtin_amdgcn_update_dpp( \
    0, __float_as_int(x), 0x120 + (j), 0xF, 0xF, true))

// Fused GRU recurrence + output projection. One batch element per wave,
// 512 blocks x 64 threads (2 waves/CU). Lane u = lane&15 owns hidden unit u;
// all 4 DPP rows redundantly compute the same recurrence (row_ror is per-row),
// so every lane holds h[lane&15] — proj replication is a v_readlane.
// Projection (out[t] = sigmoid(h_t . W_out^T + b_out)) is issued in the
// dependency-stall shadow of the next recurrence step: lane owns outputs
// {2*lane, 2*lane+1} -> wave stores 512 B contiguous per step.
__global__ __launch_bounds__(64, 1) void gru_fused(
    const float* __restrict__ feed, const float* __restrict__ h0,
    const float* __restrict__ W_ih, const float* __restrict__ W_hh,
    const float* __restrict__ b_ih, const float* __restrict__ b_hh,
    const float* __restrict__ W_out, const float* __restrict__ b_out,
    float* __restrict__ out)
{
    const int lane = threadIdx.x;      // 0..63
    const int u = lane & 15;           // hidden unit (u==15 inert)
    const int uu = (u < Hh) ? u : 0;
    const int b = blockIdx.x;          // one batch elem per block/wave

    // Probe DPP row_ror source direction once.
    int pr = __builtin_amdgcn_update_dpp(0, lane & 15, 0x121, 0xF, 0xF, true);
    const int dir = (__builtin_amdgcn_readfirstlane(pr) == 1) ? 1 : 15;

    // Per-lane rotated recurrence weights; k==15 slots zeroed.
    float Wr[16], Wz[16], Wn[16];
    #pragma unroll
    for (int j = 0; j < 16; ++j) {
        int k = (uu + dir * j) & 15;
        bool ok = (k < Hh);
        int kk = ok ? k : 0;
        Wr[j] = ok ? W_hh[(uu         ) * Hh + kk] : 0.0f;
        Wz[j] = ok ? W_hh[(uu +     Hh) * Hh + kk] : 0.0f;
        Wn[j] = ok ? W_hh[(uu + 2 * Hh) * Hh + kk] : 0.0f;
    }

    // Time-invariant input-gate constants.
    float cr = b_ih[uu]          + b_hh[uu];
    float cz = b_ih[uu + Hh]     + b_hh[uu + Hh];
    float cn = b_ih[uu + 2 * Hh];
    float bn = b_hh[uu + 2 * Hh];
    #pragma unroll
    for (int i = 0; i < Ii; ++i) {
        float x = feed[b * Ii + i];
        cr += x * W_ih[(uu         ) * Ii + i];
        cz += x * W_ih[(uu +     Hh) * Ii + i];
        cn += x * W_ih[(uu + 2 * Hh) * Ii + i];
    }

    // Projection weights: this lane owns output columns o0, o0+1.
    const int o0 = lane * 2;
    float wp0[Hh], wp1[Hh];
    #pragma unroll
    for (int k = 0; k < Hh; ++k) {
        wp0[k] = W_out[(o0    ) * Hh + k];
        wp1[k] = W_out[(o0 + 1) * Hh + k];
    }
    const float bo0 = b_out[o0], bo1 = b_out[o0 + 1];

    float hcur = (u < Hh) ? h0[b * Hh + uu] : 0.0f;
    float* outp = out + (size_t)b * Oo + o0;

    for (int t = 0; t < Tt; ++t) {
        // ---- recurrence step (serial dependency chain) ----
        float hr[16];
        hr[0]  = hcur;
        hr[1]  = ROT(hcur, 1);   hr[2]  = ROT(hcur, 2);
        hr[3]  = ROT(hcur, 3);   hr[4]  = ROT(hcur, 4);
        hr[5]  = ROT(hcur, 5);   hr[6]  = ROT(hcur, 6);
        hr[7]  = ROT(hcur, 7);   hr[8]  = ROT(hcur, 8);
        hr[9]  = ROT(hcur, 9);   hr[10] = ROT(hcur, 10);
        hr[11] = ROT(hcur, 11);  hr[12] = ROT(hcur, 12);
        hr[13] = ROT(hcur, 13);  hr[14] = ROT(hcur, 14);
        hr[15] = ROT(hcur, 15);

        float ar[4] = {cr, 0.f, 0.f, 0.f};
        float az[4] = {cz, 0.f, 0.f, 0.f};
        float an[4] = {bn, 0.f, 0.f, 0.f};
        #pragma unroll
        for (int j = 0; j < 16; ++j) {
            ar[j & 3] += Wr[j] * hr[j];
            az[j & 3] += Wz[j] * hr[j];
            an[j & 3] += Wn[j] * hr[j];
        }
        float r = sigmoidf_((ar[0] + ar[1]) + (ar[2] + ar[3]));
        float z = sigmoidf_((az[0] + az[1]) + (az[2] + az[3]));
        float dn = (an[0] + an[1]) + (an[2] + an[3]);
        float n = tanhf_(cn + r * dn);
        float hnew = n + z * (hcur - n);

        // ---- projection for this t (independent work, fills stalls) ----
        float hv[Hh];
        #pragma unroll
        for (int k = 0; k < Hh; ++k)
            hv[k] = __int_as_float(
                __builtin_amdgcn_readlane(__float_as_int(hnew), k));

        float s0a = bo0, s0b = 0.f, s1a = bo1, s1b = 0.f;
        #pragma unroll
        for (int k = 0; k < Hh; k += 2) {
            s0a += hv[k] * wp0[k];
            s1a += hv[k] * wp1[k];
        }
        #pragma unroll
        for (int k = 1; k < Hh; k += 2) {
            s0b += hv[k] * wp0[k];
            s1b += hv[k] * wp1[k];
        }
        v2f res = {sigmoidf_(s0a + s0b), sigmoidf_(s1a + s1b)};
        __builtin_nontemporal_store(res, (v2f*)outp);
        outp += (size_t)Bb * Oo;

        hcur = hnew;
    }
}

extern "C" void kernel_launch(void* const* d_in, const int* in_sizes, int n_in,
                              void* d_out, int out_size, void* d_ws, size_t ws_size,
                              hipStream_t stream) {
    const float* feed  = (const float*)d_in[0];
    const float* h0    = (const float*)d_in[1];
    const float* W_ih  = (const float*)d_in[2];
    const float* W_hh  = (const float*)d_in[3];
    const float* b_ih  = (const float*)d_in[4];
    const float* b_hh  = (const float*)d_in[5];
    const float* W_out = (const float*)d_in[6];
    const float* b_out = (const float*)d_in[7];
    float* out = (float*)d_out;

    gru_fused<<<Bb, 64, 0, stream>>>(feed, h0, W_ih, W_hh, b_ih, b_hh,
                                     W_out, b_out, out);
}